// Round 7
// baseline (183.120 us; speedup 1.0000x reference)
//
#include <hip/hip_runtime.h>
#include <hip/hip_bf16.h>

typedef __attribute__((ext_vector_type(8))) short bf16x8;
typedef __attribute__((ext_vector_type(4))) float f32x4;

constexpr int Q = 16384, S = 16384, KNN = 32, F = 64, O = 64;
constexpr int NEDGE = Q * KNN;
constexpr int QB = 8;                   // q's per main block
constexpr int EB = 256;                 // edges per block
constexpr int GD = Q / QB;              // 2048 main blocks
constexpr int GH = 256;                 // k_hsq blocks (64 s each)
constexpr float EPSV = 1e-5f;

// workspace byte offsets
constexpr size_t CNT_OFF   = 0;                                   // S ints
constexpr size_t CTR_OFF   = 65536;                               // ticket counters (64B)
constexpr size_t P0_OFF    = 65600;                               // GH*128 f32
constexpr size_t ST0_OFF   = P0_OFF + (size_t)GH * 128 * 4;       // 128 f32
constexpr size_t ZMIN_OFF  = ST0_OFF + 512;                       // Q*O f32
constexpr size_t P1_OFF    = ZMIN_OFF + (size_t)Q * O * 4;        // GD*128 f32
constexpr size_t ST1_OFF   = P1_OFF + (size_t)GD * 128 * 4;       // 128 f32
constexpr size_t W0F_OFF   = ST1_OFF + 512;                       // 8*64*8 bf16
constexpr size_t W1F_OFF   = W0F_OFF + 8192;                      // 24*64*8 bf16
constexpr size_t FEATB_OFF = W1F_OFF + 24576;                     // S*F bf16 (2MB)

__device__ __forceinline__ short f2bf(float f) {
  __hip_bfloat16 h = __float2bfloat16(f);
  short r; __builtin_memcpy(&r, &h, 2); return r;
}

// ---- fused prep: blocks 0-7 weight frags | 8-71 feat->bf16 | 72-135 LDS histogram ----
__global__ void k_prep_hist(const float* __restrict__ w0g, const float* __restrict__ w1g,
                            short* __restrict__ w0f, short* __restrict__ w1f,
                            const float* __restrict__ feat, short* __restrict__ featb,
                            const int* __restrict__ inds, int* __restrict__ cnt) {
  __shared__ int lh[S];   // 64KB, used only by hist blocks
  const int bx = blockIdx.x, tt = threadIdx.x;
  if (bx < 8) {
    const int t = bx * 256 + tt;   // 2048 entries
    const int fa = t >> 6, ln = t & 63;
    const int l4 = ln >> 4, l15 = ln & 15;
    if (fa < 8) {
      // W0 A-frags: A[m=o][k=f]; frag (mt,kk): o=16mt+l15, f=32kk+8l4+j
      const int mt = fa >> 1, kk = fa & 1;
      const int o = 16 * mt + l15, f = 32 * kk + 8 * l4;
      const float* src = w0g + o * 64 + f;
      bf16x8 pk;
#pragma unroll
      for (int j = 0; j < 8; ++j) pk[j] = f2bf(src[j]);
      *(bf16x8*)&w0f[t * 8] = pk;
    } else {
      // W1 B-frags with sigma-permuted k: frag nt=i*4+b, kk:
      // lane (l4,l15): c-col o=16b+l15; slot j -> op = 32kk + 16*(j>>2) + 4*l4 + (j&3)
      const int fb = fa - 8;                 // 0..23
      const int nt = fb >> 1, kk = fb & 1;
      const int i = nt >> 2, b = nt & 3;
      const int o = 16 * b + l15;
      const float* row = w1g + (o * 3 + i) * 64;
      const int base = 32 * kk + 4 * l4;
      bf16x8 pk;
#pragma unroll
      for (int j = 0; j < 4; ++j) pk[j] = f2bf(row[base + j]);
#pragma unroll
      for (int j = 4; j < 8; ++j) pk[j] = f2bf(row[base + 16 + (j & 3)]);
      *(bf16x8*)&w1f[(fb * 64 + ln) * 8] = pk;
    }
  } else if (bx < 72) {
    // feat f32 -> bf16, 16384 elems per block, coalesced
    const int base = (bx - 8) * 16384;
#pragma unroll
    for (int j = 0; j < 8; ++j) {
      const int i = base + j * 2048 + tt * 8;
      f32x4 a = *(const f32x4*)(feat + i);
      f32x4 b = *(const f32x4*)(feat + i + 4);
      bf16x8 pk;
      pk[0] = f2bf(a[0]); pk[1] = f2bf(a[1]); pk[2] = f2bf(a[2]); pk[3] = f2bf(a[3]);
      pk[4] = f2bf(b[0]); pk[5] = f2bf(b[1]); pk[6] = f2bf(b[2]); pk[7] = f2bf(b[3]);
      *(bf16x8*)(featb + i) = pk;
    }
  } else {
    // LDS-privatized histogram: 64 blocks x 8192 edges
    for (int c = tt; c < S; c += 256) lh[c] = 0;
    __syncthreads();
    const int4* ip = (const int4*)inds;
    const int base = (bx - 72) * 2048;
#pragma unroll
    for (int j = 0; j < 8; ++j) {
      const int4 v = ip[base + j * 256 + tt];
      if (v.x < S) atomicAdd(&lh[v.x], 1);
      if (v.y < S) atomicAdd(&lh[v.y], 1);
      if (v.z < S) atomicAdd(&lh[v.z], 1);
      if (v.w < S) atomicAdd(&lh[v.w], 1);
    }
    __syncthreads();
    for (int c = tt; c < S; c += 256) {
      const int v = lh[c];
      if (v) atomicAdd(&cnt[c], v);
    }
  }
}

// ---- BN0 stats via MFMA (h bitwise == k_main's) + fused last-block reduce -> st0 ----
__global__ void k_hsq(const short* __restrict__ featb, const int* __restrict__ cnt,
                      const short* __restrict__ w0f, float* __restrict__ p0,
                      int* __restrict__ ctr, const float* __restrict__ g0,
                      const float* __restrict__ b0, float* __restrict__ st0) {
  __shared__ float sred[4][2][64];
  __shared__ int isLast;
  const int t = threadIdx.x, blk = blockIdx.x;
  const int wv = t >> 6, ln = t & 63, l4 = ln >> 4, l15 = ln & 15;

  const bf16x8* w0v = (const bf16x8*)w0f;
  bf16x8 w0a[8];
#pragma unroll
  for (int fa = 0; fa < 8; ++fa) w0a[fa] = w0v[fa * 64 + ln];

  const int s0 = blk * 64 + wv * 16;
  const float wc = (float)cnt[s0 + l15];
  const short* fb = featb + (size_t)(s0 + l15) * F + 8 * l4;
  const bf16x8 y0 = *(const bf16x8*)(fb);
  const bf16x8 y1 = *(const bf16x8*)(fb + 32);

  float hs[4][4], hq[4][4];
#pragma unroll
  for (int mt = 0; mt < 4; ++mt) {
    f32x4 acc = {0.f, 0.f, 0.f, 0.f};
    acc = __builtin_amdgcn_mfma_f32_16x16x32_bf16(w0a[2 * mt], y0, acc, 0, 0, 0);
    acc = __builtin_amdgcn_mfma_f32_16x16x32_bf16(w0a[2 * mt + 1], y1, acc, 0, 0, 0);
#pragma unroll
    for (int r = 0; r < 4; ++r) {
      const float h = acc[r];
      hs[mt][r] = wc * h;
      hq[mt][r] = wc * h * h;
    }
  }
#pragma unroll
  for (int mt = 0; mt < 4; ++mt)
#pragma unroll
    for (int r = 0; r < 4; ++r) {
      float s = hs[mt][r], q = hq[mt][r];
#pragma unroll
      for (int d = 1; d < 16; d <<= 1) { s += __shfl_xor(s, d); q += __shfl_xor(q, d); }
      hs[mt][r] = s; hq[mt][r] = q;
    }
  if (l15 == 0) {
#pragma unroll
    for (int mt = 0; mt < 4; ++mt)
#pragma unroll
      for (int r = 0; r < 4; ++r) {
        const int o = 16 * mt + 4 * l4 + r;
        sred[wv][0][o] = hs[mt][r];
        sred[wv][1][o] = hq[mt][r];
      }
  }
  __syncthreads();
  if (t < 128) {
    const int qq = t >> 6, o = t & 63;
    p0[(size_t)blk * 128 + t] =
        sred[0][qq][o] + sred[1][qq][o] + sred[2][qq][o] + sred[3][qq][o];
  }
  // last-block reduction -> st0 (deterministic fixed order)
  __syncthreads();
  __threadfence();
  if (t == 0) isLast = (atomicAdd(&ctr[0], 1) == GH - 1);
  __syncthreads();
  if (isLast) {
    __threadfence();
    if (t < O) {
      float s = 0.f, q = 0.f;
      for (int b = 0; b < GH; ++b) {
        s += p0[(size_t)b * 128 + t];
        q += p0[(size_t)b * 128 + 64 + t];
      }
      const float invN = 1.f / (float)NEDGE;
      const float mean = s * invN;
      const float var = q * invN - mean * mean;
      const float sc = g0[t] * rsqrtf(var + EPSV);
      st0[t] = sc;
      st0[O + t] = b0[t] - mean * sc;
    }
  }
}

// ---- main MFMA pass: sigma-permuted k => H stays in registers (no LDS round-trip) ----
__launch_bounds__(256, 4)
__global__ void k_main(const float* __restrict__ qpts, const float* __restrict__ spts,
                       const short* __restrict__ featb, const int* __restrict__ inds,
                       const short* __restrict__ w0f, const short* __restrict__ w1f,
                       const float* __restrict__ st0,
                       float* __restrict__ zmax, float* __restrict__ zmin,
                       float* __restrict__ p1) {
  __shared__ __align__(16) float xs[3 * EB];      // x per edge
  __shared__ float swred[512];                    // block-sum staging

  const int t = threadIdx.x, blk = blockIdx.x;
  const int wv = t >> 6, ln = t & 63, l4 = ln >> 4, l15 = ln & 15;
  const int ebase = blk * EB;

  // ---- stage x (wave-local rows; same-wave DS ordering, no barrier needed)
  {
    const int e = t;
    const int idx = inds[ebase + e];
    const int q = blk * QB + (e >> 5);
    float x0 = 0.f, x1 = 0.f, x2 = 0.f;
    if (idx < S) {
      x0 = spts[idx * 3 + 0] - qpts[q * 3 + 0];
      x1 = spts[idx * 3 + 1] - qpts[q * 3 + 1];
      x2 = spts[idx * 3 + 2] - qpts[q * 3 + 2];
    }
    xs[0 * EB + e] = x0; xs[1 * EB + e] = x1; xs[2 * EB + e] = x2;
  }

  // W0 A-frags (L2-hot, coalesced)
  const bf16x8* w0v = (const bf16x8*)w0f;
  bf16x8 w0a[8];
#pragma unroll
  for (int fa = 0; fa < 8; ++fa) w0a[fa] = w0v[fa * 64 + ln];

  // batch idx loads
  int idxr[4];
#pragma unroll
  for (int nt = 0; nt < 4; ++nt) idxr[nt] = inds[ebase + wv * 64 + nt * 16 + l15];

  // ---- Phase A: per e-tile: gather Y, 8 MFMA, BN0+leaky, pack H frags in-register.
  // sigma(kk,l4,j) = 32kk + 16(j>>2) + 4l4 + (j&3): hA[T][kk][j] = v[2kk+(j>>2)][j&3]
  const float* scp = st0 + 4 * l4;        // sc[o=16m+4l4+r] = scp[16m+r]
  const float* shp = st0 + O + 4 * l4;
  bf16x8 hA[4][2];
#pragma unroll
  for (int T = 0; T < 4; ++T) {
    bf16x8 y0, y1;
    if (idxr[T] < S) {
      const short* fbp = featb + (size_t)idxr[T] * F + 8 * l4;
      y0 = *(const bf16x8*)(fbp);
      y1 = *(const bf16x8*)(fbp + 32);
    } else {
#pragma unroll
      for (int j = 0; j < 8; ++j) { y0[j] = 0; y1[j] = 0; }
    }
#pragma unroll
    for (int kk = 0; kk < 2; ++kk) {
      f32x4 a0 = {0.f, 0.f, 0.f, 0.f}, a1 = {0.f, 0.f, 0.f, 0.f};
      a0 = __builtin_amdgcn_mfma_f32_16x16x32_bf16(w0a[4 * kk + 0], y0, a0, 0, 0, 0);
      a0 = __builtin_amdgcn_mfma_f32_16x16x32_bf16(w0a[4 * kk + 1], y1, a0, 0, 0, 0);
      a1 = __builtin_amdgcn_mfma_f32_16x16x32_bf16(w0a[4 * kk + 2], y0, a1, 0, 0, 0);
      a1 = __builtin_amdgcn_mfma_f32_16x16x32_bf16(w0a[4 * kk + 3], y1, a1, 0, 0, 0);
      const f32x4 sc0 = *(const f32x4*)(scp + 32 * kk);
      const f32x4 sh0 = *(const f32x4*)(shp + 32 * kk);
      const f32x4 sc1 = *(const f32x4*)(scp + 32 * kk + 16);
      const f32x4 sh1 = *(const f32x4*)(shp + 32 * kk + 16);
      bf16x8 h;
#pragma unroll
      for (int r = 0; r < 4; ++r) {
        float v = a0[r] * sc0[r] + sh0[r];
        v = fmaxf(v, 0.1f * v);
        h[r] = f2bf(v);
      }
#pragma unroll
      for (int r = 0; r < 4; ++r) {
        float v = a1[r] * sc1[r] + sh1[r];
        v = fmaxf(v, 0.1f * v);
        h[4 + r] = f2bf(v);
      }
      hA[T][kk] = h;
    }
  }

  const bf16x8* w1v = (const bf16x8*)w1f;
  float zmx[2][4], zmn[2][4], zs[4], zq[4];
#pragma unroll
  for (int j = 0; j < 4; ++j) {
    zs[j] = 0.f; zq[j] = 0.f;
    zmx[0][j] = -3.4e38f; zmx[1][j] = -3.4e38f;
    zmn[0][j] = 3.4e38f;  zmn[1][j] = 3.4e38f;
  }

  // ---- Phase B: D2[e][c=i*64+o] = H * W1p (sigma-consistent) ; combine with x ; stats
#pragma unroll
  for (int b = 0; b < 4; ++b) {
    bf16x8 w1b[6];
#pragma unroll
    for (int i = 0; i < 3; ++i)
#pragma unroll
      for (int kk = 0; kk < 2; ++kk)
        w1b[i * 2 + kk] = w1v[(((i * 4 + b) * 2) + kk) * 64 + ln];
#pragma unroll
    for (int mt = 0; mt < 4; ++mt) {
      const int ex = wv * 64 + mt * 16 + 4 * l4;
      f32x4 z4 = {0.f, 0.f, 0.f, 0.f};
#pragma unroll
      for (int i = 0; i < 3; ++i) {
        f32x4 acc = {0.f, 0.f, 0.f, 0.f};
        acc = __builtin_amdgcn_mfma_f32_16x16x32_bf16(hA[mt][0], w1b[2 * i], acc, 0, 0, 0);
        acc = __builtin_amdgcn_mfma_f32_16x16x32_bf16(hA[mt][1], w1b[2 * i + 1], acc, 0, 0, 0);
        const f32x4 xv = *(const f32x4*)&xs[i * EB + ex];
#pragma unroll
        for (int r = 0; r < 4; ++r) z4[r] += acc[r] * xv[r];
      }
      const int qh = mt >> 1;
#pragma unroll
      for (int r = 0; r < 4; ++r) {
        const float v = z4[r];
        zmx[qh][b] = fmaxf(zmx[qh][b], v);
        zmn[qh][b] = fminf(zmn[qh][b], v);
        zs[b] += v; zq[b] += v * v;
      }
    }
  }

  // ---- cross-group (l4) reductions: lanes l, l^16, l^32 share (q-range, c)
#pragma unroll
  for (int qh = 0; qh < 2; ++qh)
#pragma unroll
    for (int b = 0; b < 4; ++b) {
      float m = zmx[qh][b];
      m = fmaxf(m, __shfl_xor(m, 16)); m = fmaxf(m, __shfl_xor(m, 32));
      zmx[qh][b] = m;
      float n = zmn[qh][b];
      n = fminf(n, __shfl_xor(n, 16)); n = fminf(n, __shfl_xor(n, 32));
      zmn[qh][b] = n;
    }
#pragma unroll
  for (int b = 0; b < 4; ++b) {
    float s = zs[b];  s += __shfl_xor(s, 16);  s += __shfl_xor(s, 32);  zs[b] = s;
    float sq = zq[b]; sq += __shfl_xor(sq, 16); sq += __shfl_xor(sq, 32); zq[b] = sq;
  }

  if (l4 == 0) {
#pragma unroll
    for (int qh = 0; qh < 2; ++qh) {
      const int q = blk * QB + wv * 2 + qh;
#pragma unroll
      for (int b = 0; b < 4; ++b) {
        zmax[(size_t)q * O + 16 * b + l15] = zmx[qh][b];
        zmin[(size_t)q * O + 16 * b + l15] = zmn[qh][b];
      }
    }
#pragma unroll
    for (int b = 0; b < 4; ++b) {
      swred[wv * 128 + 16 * b + l15] = zs[b];
      swred[wv * 128 + 64 + 16 * b + l15] = zq[b];
    }
  }
  __syncthreads();
  if (t < 128)
    p1[(size_t)blk * 128 + t] = swred[t] + swred[128 + t] + swred[256 + t] + swred[384 + t];
}

// ---- reduce z stats + BN1 scale/shift ----
__global__ void k_red1(const float* __restrict__ p1, const float* __restrict__ g1,
                       const float* __restrict__ b1, float* __restrict__ st1) {
  __shared__ float rs[256], rq[256];
  const int o = blockIdx.x, t = threadIdx.x;
  float s = 0.f, q = 0.f;
  for (int r = t; r < GD; r += 256) {
    s += p1[(size_t)r * 128 + o];
    q += p1[(size_t)r * 128 + 64 + o];
  }
  rs[t] = s; rq[t] = q;
  __syncthreads();
  for (int off = 128; off > 0; off >>= 1) {
    if (t < off) { rs[t] += rs[t + off]; rq[t] += rq[t + off]; }
    __syncthreads();
  }
  if (t == 0) {
    const float invN = 1.f / (float)NEDGE;
    const float mean = rs[0] * invN;
    const float var = rq[0] * invN - mean * mean;
    const float sc = g1[o] * rsqrtf(var + EPSV);
    st1[o] = sc;
    st1[O + o] = b1[o] - mean * sc;
  }
}

// ---- finalize: pick max/min by scale sign, affine + leaky (vectorized) ----
__global__ void k_final(const float* __restrict__ st1, const float* __restrict__ zmin,
                        float* __restrict__ out) {
  const int i4 = blockIdx.x * blockDim.x + threadIdx.x;   // Q*O/4 elements
  const int o0 = (i4 * 4) & 63;
  const f32x4 mx = *(const f32x4*)(out + (size_t)i4 * 4);   // holds zmax
  const f32x4 mn = *(const f32x4*)(zmin + (size_t)i4 * 4);
  const f32x4 sc = *(const f32x4*)(st1 + o0);
  const f32x4 sh = *(const f32x4*)(st1 + O + o0);
  f32x4 r;
#pragma unroll
  for (int j = 0; j < 4; ++j) {
    const float base = (sc[j] >= 0.f) ? mx[j] : mn[j];
    const float v = base * sc[j] + sh[j];
    r[j] = fmaxf(v, 0.1f * v);
  }
  *(f32x4*)(out + (size_t)i4 * 4) = r;
}

extern "C" void kernel_launch(void* const* d_in, const int* in_sizes, int n_in,
                              void* d_out, int out_size, void* d_ws, size_t ws_size,
                              hipStream_t stream) {
  const float* qpts = (const float*)d_in[0];
  const float* spts = (const float*)d_in[1];
  const float* feat = (const float*)d_in[2];
  const int*   inds = (const int*)d_in[3];
  const float* w0   = (const float*)d_in[4];
  const float* g0   = (const float*)d_in[5];
  const float* b0   = (const float*)d_in[6];
  const float* w1   = (const float*)d_in[7];
  const float* g1   = (const float*)d_in[8];
  const float* b1   = (const float*)d_in[9];
  float* out = (float*)d_out;

  char* ws = (char*)d_ws;
  int*   cnt   = (int*)(ws + CNT_OFF);
  int*   ctr   = (int*)(ws + CTR_OFF);
  float* p0    = (float*)(ws + P0_OFF);
  float* st0   = (float*)(ws + ST0_OFF);
  float* zmin  = (float*)(ws + ZMIN_OFF);
  float* p1    = (float*)(ws + P1_OFF);
  float* st1   = (float*)(ws + ST1_OFF);
  short* w0f   = (short*)(ws + W0F_OFF);
  short* w1f   = (short*)(ws + W1F_OFF);
  short* featb = (short*)(ws + FEATB_OFF);

  hipMemsetAsync(ws, 0, CTR_OFF + 64, stream);   // cnt + ticket counters
  k_prep_hist<<<136, 256, 0, stream>>>(w0, w1, w0f, w1f, feat, featb, inds, cnt);
  k_hsq<<<GH, 256, 0, stream>>>(featb, cnt, w0f, p0, ctr, g0, b0, st0);
  k_main<<<GD, 256, 0, stream>>>(qpts, spts, featb, inds, w0f, w1f, st0, out, zmin, p1);
  k_red1<<<64, 256, 0, stream>>>(p1, g1, b1, st1);
  k_final<<<(Q * O) / 1024, 256, 0, stream>>>(st1, zmin, out);
}

// Round 8
// 97.697 us; speedup vs baseline: 1.8744x; 1.8744x over previous
//
#include <hip/hip_runtime.h>
#include <hip/hip_bf16.h>

typedef __attribute__((ext_vector_type(8))) short bf16x8;
typedef __attribute__((ext_vector_type(4))) float f32x4;

constexpr int Q = 16384, S = 16384, KNN = 32, F = 64, O = 64;
constexpr int NEDGE = Q * KNN;
constexpr int QB = 8;                   // q's per main block
constexpr int EB = 256;                 // edges per block
constexpr int GD = Q / QB;              // 2048 main blocks
constexpr int GH = 256;                 // k_hsq blocks (64 s each)
constexpr float EPSV = 1e-5f;

// workspace byte offsets
constexpr size_t CNT_OFF   = 0;                                   // S ints
constexpr size_t CTR_OFF   = 65536;                               // ticket counters (64B)
constexpr size_t P0_OFF    = 65600;                               // GH*128 f32
constexpr size_t ST0_OFF   = P0_OFF + (size_t)GH * 128 * 4;       // 128 f32
constexpr size_t ZMIN_OFF  = ST0_OFF + 512;                       // Q*O f32
constexpr size_t P1_OFF    = ZMIN_OFF + (size_t)Q * O * 4;        // GD*128 f32
constexpr size_t ST1_OFF   = P1_OFF + (size_t)GD * 128 * 4;       // 128 f32
constexpr size_t W0F_OFF   = ST1_OFF + 512;                       // 8*64*8 bf16
constexpr size_t W1F_OFF   = W0F_OFF + 8192;                      // 24*64*8 bf16
constexpr size_t FEATB_OFF = W1F_OFF + 24576;                     // S*F bf16 (2MB)

__device__ __forceinline__ short f2bf(float f) {
  __hip_bfloat16 h = __float2bfloat16(f);
  short r; __builtin_memcpy(&r, &h, 2); return r;
}

// ---- fused prep: blocks 0-7 weight frags | 8-71 feat->bf16 | 72-135 LDS histogram ----
__global__ void k_prep_hist(const float* __restrict__ w0g, const float* __restrict__ w1g,
                            short* __restrict__ w0f, short* __restrict__ w1f,
                            const float* __restrict__ feat, short* __restrict__ featb,
                            const int* __restrict__ inds, int* __restrict__ cnt) {
  __shared__ int lh[S];   // 64KB, used only by hist blocks
  const int bx = blockIdx.x, tt = threadIdx.x;
  if (bx < 8) {
    const int t = bx * 256 + tt;   // 2048 entries
    const int fa = t >> 6, ln = t & 63;
    const int l4 = ln >> 4, l15 = ln & 15;
    if (fa < 8) {
      // W0 A-frags: A[m=o][k=f]; frag (mt,kk): o=16mt+l15, f=32kk+8l4+j
      const int mt = fa >> 1, kk = fa & 1;
      const int o = 16 * mt + l15, f = 32 * kk + 8 * l4;
      const float* src = w0g + o * 64 + f;
      bf16x8 pk;
#pragma unroll
      for (int j = 0; j < 8; ++j) pk[j] = f2bf(src[j]);
      *(bf16x8*)&w0f[t * 8] = pk;
    } else {
      // W1 B-frags with sigma-permuted k: frag nt=i*4+b, kk:
      // lane (l4,l15): c-col o=16b+l15; slot j -> op = 32kk + 16*(j>>2) + 4*l4 + (j&3)
      const int fb = fa - 8;                 // 0..23
      const int nt = fb >> 1, kk = fb & 1;
      const int i = nt >> 2, b = nt & 3;
      const int o = 16 * b + l15;
      const float* row = w1g + (o * 3 + i) * 64;
      const int base = 32 * kk + 4 * l4;
      bf16x8 pk;
#pragma unroll
      for (int j = 0; j < 4; ++j) pk[j] = f2bf(row[base + j]);
#pragma unroll
      for (int j = 4; j < 8; ++j) pk[j] = f2bf(row[base + 16 + (j & 3)]);
      *(bf16x8*)&w1f[(fb * 64 + ln) * 8] = pk;
    }
  } else if (bx < 72) {
    // feat f32 -> bf16, 16384 elems per block, coalesced
    const int base = (bx - 8) * 16384;
#pragma unroll
    for (int j = 0; j < 8; ++j) {
      const int i = base + j * 2048 + tt * 8;
      f32x4 a = *(const f32x4*)(feat + i);
      f32x4 b = *(const f32x4*)(feat + i + 4);
      bf16x8 pk;
      pk[0] = f2bf(a[0]); pk[1] = f2bf(a[1]); pk[2] = f2bf(a[2]); pk[3] = f2bf(a[3]);
      pk[4] = f2bf(b[0]); pk[5] = f2bf(b[1]); pk[6] = f2bf(b[2]); pk[7] = f2bf(b[3]);
      *(bf16x8*)(featb + i) = pk;
    }
  } else {
    // LDS-privatized histogram: 64 blocks x 8192 edges
    for (int c = tt; c < S; c += 256) lh[c] = 0;
    __syncthreads();
    const int4* ip = (const int4*)inds;
    const int base = (bx - 72) * 2048;
#pragma unroll
    for (int j = 0; j < 8; ++j) {
      const int4 v = ip[base + j * 256 + tt];
      if (v.x < S) atomicAdd(&lh[v.x], 1);
      if (v.y < S) atomicAdd(&lh[v.y], 1);
      if (v.z < S) atomicAdd(&lh[v.z], 1);
      if (v.w < S) atomicAdd(&lh[v.w], 1);
    }
    __syncthreads();
    for (int c = tt; c < S; c += 256) {
      const int v = lh[c];
      if (v) atomicAdd(&cnt[c], v);
    }
  }
}

// ---- BN0 stats via MFMA (h bitwise == k_main's) + fused last-block reduce -> st0 ----
__global__ void k_hsq(const short* __restrict__ featb, const int* __restrict__ cnt,
                      const short* __restrict__ w0f, float* __restrict__ p0,
                      int* __restrict__ ctr, const float* __restrict__ g0,
                      const float* __restrict__ b0, float* __restrict__ st0) {
  __shared__ float sred[4][2][64];
  __shared__ int isLast;
  const int t = threadIdx.x, blk = blockIdx.x;
  const int wv = t >> 6, ln = t & 63, l4 = ln >> 4, l15 = ln & 15;

  const bf16x8* w0v = (const bf16x8*)w0f;
  bf16x8 w0a[8];
#pragma unroll
  for (int fa = 0; fa < 8; ++fa) w0a[fa] = w0v[fa * 64 + ln];

  const int s0 = blk * 64 + wv * 16;
  const float wc = (float)cnt[s0 + l15];
  const short* fb = featb + (size_t)(s0 + l15) * F + 8 * l4;
  const bf16x8 y0 = *(const bf16x8*)(fb);
  const bf16x8 y1 = *(const bf16x8*)(fb + 32);

  float hs[4][4], hq[4][4];
#pragma unroll
  for (int mt = 0; mt < 4; ++mt) {
    f32x4 acc = {0.f, 0.f, 0.f, 0.f};
    acc = __builtin_amdgcn_mfma_f32_16x16x32_bf16(w0a[2 * mt], y0, acc, 0, 0, 0);
    acc = __builtin_amdgcn_mfma_f32_16x16x32_bf16(w0a[2 * mt + 1], y1, acc, 0, 0, 0);
#pragma unroll
    for (int r = 0; r < 4; ++r) {
      const float h = acc[r];
      hs[mt][r] = wc * h;
      hq[mt][r] = wc * h * h;
    }
  }
#pragma unroll
  for (int mt = 0; mt < 4; ++mt)
#pragma unroll
    for (int r = 0; r < 4; ++r) {
      float s = hs[mt][r], q = hq[mt][r];
#pragma unroll
      for (int d = 1; d < 16; d <<= 1) { s += __shfl_xor(s, d); q += __shfl_xor(q, d); }
      hs[mt][r] = s; hq[mt][r] = q;
    }
  if (l15 == 0) {
#pragma unroll
    for (int mt = 0; mt < 4; ++mt)
#pragma unroll
      for (int r = 0; r < 4; ++r) {
        const int o = 16 * mt + 4 * l4 + r;
        sred[wv][0][o] = hs[mt][r];
        sred[wv][1][o] = hq[mt][r];
      }
  }
  __syncthreads();
  if (t < 128) {
    const int qq = t >> 6, o = t & 63;
    p0[(size_t)blk * 128 + t] =
        sred[0][qq][o] + sred[1][qq][o] + sred[2][qq][o] + sred[3][qq][o];
  }
  // last-block reduction -> st0 (deterministic fixed order)
  __syncthreads();
  __threadfence();
  if (t == 0) isLast = (atomicAdd(&ctr[0], 1) == GH - 1);
  __syncthreads();
  if (isLast) {
    __threadfence();
    if (t < O) {
      float s = 0.f, q = 0.f;
      for (int b = 0; b < GH; ++b) {
        s += p0[(size_t)b * 128 + t];
        q += p0[(size_t)b * 128 + 64 + t];
      }
      const float invN = 1.f / (float)NEDGE;
      const float mean = s * invN;
      const float var = q * invN - mean * mean;
      const float sc = g0[t] * rsqrtf(var + EPSV);
      st0[t] = sc;
      st0[O + t] = b0[t] - mean * sc;
    }
  }
}

// ---- main MFMA pass: sigma-permuted k => H stays in registers (no LDS round-trip) ----
__launch_bounds__(256, 3)
__global__ void k_main(const float* __restrict__ qpts, const float* __restrict__ spts,
                       const short* __restrict__ featb, const int* __restrict__ inds,
                       const short* __restrict__ w0f, const short* __restrict__ w1f,
                       const float* __restrict__ st0,
                       float* __restrict__ zmax, float* __restrict__ zmin,
                       float* __restrict__ p1) {
  __shared__ __align__(16) float xs[3 * EB];      // x per edge
  __shared__ float swred[512];                    // block-sum staging

  const int t = threadIdx.x, blk = blockIdx.x;
  const int wv = t >> 6, ln = t & 63, l4 = ln >> 4, l15 = ln & 15;
  const int ebase = blk * EB;

  // ---- stage x (wave-local rows; same-wave DS ordering, no barrier needed)
  {
    const int e = t;
    const int idx = inds[ebase + e];
    const int q = blk * QB + (e >> 5);
    float x0 = 0.f, x1 = 0.f, x2 = 0.f;
    if (idx < S) {
      x0 = spts[idx * 3 + 0] - qpts[q * 3 + 0];
      x1 = spts[idx * 3 + 1] - qpts[q * 3 + 1];
      x2 = spts[idx * 3 + 2] - qpts[q * 3 + 2];
    }
    xs[0 * EB + e] = x0; xs[1 * EB + e] = x1; xs[2 * EB + e] = x2;
  }

  // W0 A-frags (L2-hot, coalesced)
  const bf16x8* w0v = (const bf16x8*)w0f;
  bf16x8 w0a[8];
#pragma unroll
  for (int fa = 0; fa < 8; ++fa) w0a[fa] = w0v[fa * 64 + ln];

  // batch idx loads
  int idxr[4];
#pragma unroll
  for (int nt = 0; nt < 4; ++nt) idxr[nt] = inds[ebase + wv * 64 + nt * 16 + l15];

  // ---- Phase A: per e-tile: gather Y, 8 MFMA, BN0+leaky, pack H frags in-register.
  // sigma(kk,l4,j) = 32kk + 16(j>>2) + 4l4 + (j&3): hA[T][kk][j] = v[2kk+(j>>2)][j&3]
  const float* scp = st0 + 4 * l4;        // sc[o=16m+4l4+r] = scp[16m+r]
  const float* shp = st0 + O + 4 * l4;
  bf16x8 hA[4][2];
#pragma unroll
  for (int T = 0; T < 4; ++T) {
    bf16x8 y0, y1;
    if (idxr[T] < S) {
      const short* fbp = featb + (size_t)idxr[T] * F + 8 * l4;
      y0 = *(const bf16x8*)(fbp);
      y1 = *(const bf16x8*)(fbp + 32);
    } else {
#pragma unroll
      for (int j = 0; j < 8; ++j) { y0[j] = 0; y1[j] = 0; }
    }
#pragma unroll
    for (int kk = 0; kk < 2; ++kk) {
      f32x4 a0 = {0.f, 0.f, 0.f, 0.f}, a1 = {0.f, 0.f, 0.f, 0.f};
      a0 = __builtin_amdgcn_mfma_f32_16x16x32_bf16(w0a[4 * kk + 0], y0, a0, 0, 0, 0);
      a0 = __builtin_amdgcn_mfma_f32_16x16x32_bf16(w0a[4 * kk + 1], y1, a0, 0, 0, 0);
      a1 = __builtin_amdgcn_mfma_f32_16x16x32_bf16(w0a[4 * kk + 2], y0, a1, 0, 0, 0);
      a1 = __builtin_amdgcn_mfma_f32_16x16x32_bf16(w0a[4 * kk + 3], y1, a1, 0, 0, 0);
      const f32x4 sc0 = *(const f32x4*)(scp + 32 * kk);
      const f32x4 sh0 = *(const f32x4*)(shp + 32 * kk);
      const f32x4 sc1 = *(const f32x4*)(scp + 32 * kk + 16);
      const f32x4 sh1 = *(const f32x4*)(shp + 32 * kk + 16);
      bf16x8 h;
#pragma unroll
      for (int r = 0; r < 4; ++r) {
        float v = a0[r] * sc0[r] + sh0[r];
        v = fmaxf(v, 0.1f * v);
        h[r] = f2bf(v);
      }
#pragma unroll
      for (int r = 0; r < 4; ++r) {
        float v = a1[r] * sc1[r] + sh1[r];
        v = fmaxf(v, 0.1f * v);
        h[4 + r] = f2bf(v);
      }
      hA[T][kk] = h;
    }
  }

  const bf16x8* w1v = (const bf16x8*)w1f;
  float zmx[2][4], zmn[2][4], zs[4], zq[4];
#pragma unroll
  for (int j = 0; j < 4; ++j) {
    zs[j] = 0.f; zq[j] = 0.f;
    zmx[0][j] = -3.4e38f; zmx[1][j] = -3.4e38f;
    zmn[0][j] = 3.4e38f;  zmn[1][j] = 3.4e38f;
  }

  // ---- Phase B: D2[e][c=i*64+o] = H * W1p (sigma-consistent) ; combine with x ; stats
#pragma unroll
  for (int b = 0; b < 4; ++b) {
    bf16x8 w1b[6];
#pragma unroll
    for (int i = 0; i < 3; ++i)
#pragma unroll
      for (int kk = 0; kk < 2; ++kk)
        w1b[i * 2 + kk] = w1v[(((i * 4 + b) * 2) + kk) * 64 + ln];
#pragma unroll
    for (int mt = 0; mt < 4; ++mt) {
      const int ex = wv * 64 + mt * 16 + 4 * l4;
      f32x4 z4 = {0.f, 0.f, 0.f, 0.f};
#pragma unroll
      for (int i = 0; i < 3; ++i) {
        f32x4 acc = {0.f, 0.f, 0.f, 0.f};
        acc = __builtin_amdgcn_mfma_f32_16x16x32_bf16(hA[mt][0], w1b[2 * i], acc, 0, 0, 0);
        acc = __builtin_amdgcn_mfma_f32_16x16x32_bf16(hA[mt][1], w1b[2 * i + 1], acc, 0, 0, 0);
        const f32x4 xv = *(const f32x4*)&xs[i * EB + ex];
#pragma unroll
        for (int r = 0; r < 4; ++r) z4[r] += acc[r] * xv[r];
      }
      const int qh = mt >> 1;
#pragma unroll
      for (int r = 0; r < 4; ++r) {
        const float v = z4[r];
        zmx[qh][b] = fmaxf(zmx[qh][b], v);
        zmn[qh][b] = fminf(zmn[qh][b], v);
        zs[b] += v; zq[b] += v * v;
      }
    }
  }

  // ---- cross-group (l4) reductions: lanes l, l^16, l^32 share (q-range, c)
#pragma unroll
  for (int qh = 0; qh < 2; ++qh)
#pragma unroll
    for (int b = 0; b < 4; ++b) {
      float m = zmx[qh][b];
      m = fmaxf(m, __shfl_xor(m, 16)); m = fmaxf(m, __shfl_xor(m, 32));
      zmx[qh][b] = m;
      float n = zmn[qh][b];
      n = fminf(n, __shfl_xor(n, 16)); n = fminf(n, __shfl_xor(n, 32));
      zmn[qh][b] = n;
    }
#pragma unroll
  for (int b = 0; b < 4; ++b) {
    float s = zs[b];  s += __shfl_xor(s, 16);  s += __shfl_xor(s, 32);  zs[b] = s;
    float sq = zq[b]; sq += __shfl_xor(sq, 16); sq += __shfl_xor(sq, 32); zq[b] = sq;
  }

  if (l4 == 0) {
#pragma unroll
    for (int qh = 0; qh < 2; ++qh) {
      const int q = blk * QB + wv * 2 + qh;
#pragma unroll
      for (int b = 0; b < 4; ++b) {
        zmax[(size_t)q * O + 16 * b + l15] = zmx[qh][b];
        zmin[(size_t)q * O + 16 * b + l15] = zmn[qh][b];
      }
    }
#pragma unroll
    for (int b = 0; b < 4; ++b) {
      swred[wv * 128 + 16 * b + l15] = zs[b];
      swred[wv * 128 + 64 + 16 * b + l15] = zq[b];
    }
  }
  __syncthreads();
  if (t < 128)
    p1[(size_t)blk * 128 + t] = swred[t] + swred[128 + t] + swred[256 + t] + swred[384 + t];
}

// ---- reduce z stats + BN1 scale/shift ----
__global__ void k_red1(const float* __restrict__ p1, const float* __restrict__ g1,
                       const float* __restrict__ b1, float* __restrict__ st1) {
  __shared__ float rs[256], rq[256];
  const int o = blockIdx.x, t = threadIdx.x;
  float s = 0.f, q = 0.f;
  for (int r = t; r < GD; r += 256) {
    s += p1[(size_t)r * 128 + o];
    q += p1[(size_t)r * 128 + 64 + o];
  }
  rs[t] = s; rq[t] = q;
  __syncthreads();
  for (int off = 128; off > 0; off >>= 1) {
    if (t < off) { rs[t] += rs[t + off]; rq[t] += rq[t + off]; }
    __syncthreads();
  }
  if (t == 0) {
    const float invN = 1.f / (float)NEDGE;
    const float mean = rs[0] * invN;
    const float var = rq[0] * invN - mean * mean;
    const float sc = g1[o] * rsqrtf(var + EPSV);
    st1[o] = sc;
    st1[O + o] = b1[o] - mean * sc;
  }
}

// ---- finalize: pick max/min by scale sign, affine + leaky (vectorized) ----
__global__ void k_final(const float* __restrict__ st1, const float* __restrict__ zmin,
                        float* __restrict__ out) {
  const int i4 = blockIdx.x * blockDim.x + threadIdx.x;   // Q*O/4 elements
  const int o0 = (i4 * 4) & 63;
  const f32x4 mx = *(const f32x4*)(out + (size_t)i4 * 4);   // holds zmax
  const f32x4 mn = *(const f32x4*)(zmin + (size_t)i4 * 4);
  const f32x4 sc = *(const f32x4*)(st1 + o0);
  const f32x4 sh = *(const f32x4*)(st1 + O + o0);
  f32x4 r;
#pragma unroll
  for (int j = 0; j < 4; ++j) {
    const float base = (sc[j] >= 0.f) ? mx[j] : mn[j];
    const float v = base * sc[j] + sh[j];
    r[j] = fmaxf(v, 0.1f * v);
  }
  *(f32x4*)(out + (size_t)i4 * 4) = r;
}

extern "C" void kernel_launch(void* const* d_in, const int* in_sizes, int n_in,
                              void* d_out, int out_size, void* d_ws, size_t ws_size,
                              hipStream_t stream) {
  const float* qpts = (const float*)d_in[0];
  const float* spts = (const float*)d_in[1];
  const float* feat = (const float*)d_in[2];
  const int*   inds = (const int*)d_in[3];
  const float* w0   = (const float*)d_in[4];
  const float* g0   = (const float*)d_in[5];
  const float* b0   = (const float*)d_in[6];
  const float* w1   = (const float*)d_in[7];
  const float* g1   = (const float*)d_in[8];
  const float* b1   = (const float*)d_in[9];
  float* out = (float*)d_out;

  char* ws = (char*)d_ws;
  int*   cnt   = (int*)(ws + CNT_OFF);
  int*   ctr   = (int*)(ws + CTR_OFF);
  float* p0    = (float*)(ws + P0_OFF);
  float* st0   = (float*)(ws + ST0_OFF);
  float* zmin  = (float*)(ws + ZMIN_OFF);
  float* p1    = (float*)(ws + P1_OFF);
  float* st1   = (float*)(ws + ST1_OFF);
  short* w0f   = (short*)(ws + W0F_OFF);
  short* w1f   = (short*)(ws + W1F_OFF);
  short* featb = (short*)(ws + FEATB_OFF);

  hipMemsetAsync(ws, 0, CTR_OFF + 64, stream);   // cnt + ticket counters
  k_prep_hist<<<136, 256, 0, stream>>>(w0, w1, w0f, w1f, feat, featb, inds, cnt);
  k_hsq<<<GH, 256, 0, stream>>>(featb, cnt, w0f, p0, ctr, g0, b0, st0);
  k_main<<<GD, 256, 0, stream>>>(qpts, spts, featb, inds, w0f, w1f, st0, out, zmin, p1);
  k_red1<<<64, 256, 0, stream>>>(p1, g1, b1, st1);
  k_final<<<(Q * O) / 1024, 256, 0, stream>>>(st1, zmin, out);
}

// Round 9
// 87.986 us; speedup vs baseline: 2.0812x; 1.1104x over previous
//
#include <hip/hip_runtime.h>
#include <hip/hip_bf16.h>

typedef __attribute__((ext_vector_type(8))) short bf16x8;
typedef __attribute__((ext_vector_type(4))) float f32x4;

constexpr int Q = 16384, S = 16384, KNN = 32, F = 64, O = 64;
constexpr int NEDGE = Q * KNN;
constexpr int QB = 8;                   // q's per main block
constexpr int EB = 256;                 // edges per block
constexpr int GD = Q / QB;              // 2048 main blocks
constexpr int GH = 256;                 // k_hsq blocks (64 s each)
constexpr float EPSV = 1e-5f;

// workspace byte offsets
constexpr size_t CNT_OFF   = 0;                                   // S ints
constexpr size_t CTR_OFF   = 65536;                               // ticket counters (64B)
constexpr size_t P0_OFF    = 65600;                               // GH*128 f32
constexpr size_t ST0_OFF   = P0_OFF + (size_t)GH * 128 * 4;       // 128 f32
constexpr size_t ZMIN_OFF  = ST0_OFF + 512;                       // Q*O f32
constexpr size_t P1_OFF    = ZMIN_OFF + (size_t)Q * O * 4;        // GD*128 f32
constexpr size_t ST1_OFF   = P1_OFF + (size_t)GD * 128 * 4;       // 128 f32
constexpr size_t W0F_OFF   = ST1_OFF + 512;                       // 8*64*8 bf16
constexpr size_t W1F_OFF   = W0F_OFF + 8192;                      // 24*64*8 bf16
constexpr size_t FEATB_OFF = W1F_OFF + 24576;                     // S*F bf16 (2MB)

__device__ __forceinline__ short f2bf(float f) {
  __hip_bfloat16 h = __float2bfloat16(f);
  short r; __builtin_memcpy(&r, &h, 2); return r;
}

// ---- fused prep: blocks 0-7 weight frags | 8-71 feat->bf16 | 72-135 LDS histogram ----
__global__ void k_prep_hist(const float* __restrict__ w0g, const float* __restrict__ w1g,
                            short* __restrict__ w0f, short* __restrict__ w1f,
                            const float* __restrict__ feat, short* __restrict__ featb,
                            const int* __restrict__ inds, int* __restrict__ cnt) {
  __shared__ int lh[S];   // 64KB, used only by hist blocks
  const int bx = blockIdx.x, tt = threadIdx.x;
  if (bx < 8) {
    const int t = bx * 256 + tt;   // 2048 entries
    const int fa = t >> 6, ln = t & 63;
    const int l4 = ln >> 4, l15 = ln & 15;
    if (fa < 8) {
      // W0 A-frags: A[m=o][k=f]; frag (mt,kk): o=16mt+l15, f=32kk+8l4+j
      const int mt = fa >> 1, kk = fa & 1;
      const int o = 16 * mt + l15, f = 32 * kk + 8 * l4;
      const float* src = w0g + o * 64 + f;
      bf16x8 pk;
#pragma unroll
      for (int j = 0; j < 8; ++j) pk[j] = f2bf(src[j]);
      *(bf16x8*)&w0f[t * 8] = pk;
    } else {
      // W1 B-frags with sigma-permuted k: frag nt=i*4+b, kk:
      // lane (l4,l15): c-col o=16b+l15; slot j -> op = 32kk + 16*(j>>2) + 4*l4 + (j&3)
      const int fb = fa - 8;                 // 0..23
      const int nt = fb >> 1, kk = fb & 1;
      const int i = nt >> 2, b = nt & 3;
      const int o = 16 * b + l15;
      const float* row = w1g + (o * 3 + i) * 64;
      const int base = 32 * kk + 4 * l4;
      bf16x8 pk;
#pragma unroll
      for (int j = 0; j < 4; ++j) pk[j] = f2bf(row[base + j]);
#pragma unroll
      for (int j = 4; j < 8; ++j) pk[j] = f2bf(row[base + 16 + (j & 3)]);
      *(bf16x8*)&w1f[(fb * 64 + ln) * 8] = pk;
    }
  } else if (bx < 72) {
    // feat f32 -> bf16, 16384 elems per block, coalesced
    const int base = (bx - 8) * 16384;
#pragma unroll
    for (int j = 0; j < 8; ++j) {
      const int i = base + j * 2048 + tt * 8;
      f32x4 a = *(const f32x4*)(feat + i);
      f32x4 b = *(const f32x4*)(feat + i + 4);
      bf16x8 pk;
      pk[0] = f2bf(a[0]); pk[1] = f2bf(a[1]); pk[2] = f2bf(a[2]); pk[3] = f2bf(a[3]);
      pk[4] = f2bf(b[0]); pk[5] = f2bf(b[1]); pk[6] = f2bf(b[2]); pk[7] = f2bf(b[3]);
      *(bf16x8*)(featb + i) = pk;
    }
  } else {
    // LDS-privatized histogram: 64 blocks x 8192 edges
    for (int c = tt; c < S; c += 256) lh[c] = 0;
    __syncthreads();
    const int4* ip = (const int4*)inds;
    const int base = (bx - 72) * 2048;
#pragma unroll
    for (int j = 0; j < 8; ++j) {
      const int4 v = ip[base + j * 256 + tt];
      if (v.x < S) atomicAdd(&lh[v.x], 1);
      if (v.y < S) atomicAdd(&lh[v.y], 1);
      if (v.z < S) atomicAdd(&lh[v.z], 1);
      if (v.w < S) atomicAdd(&lh[v.w], 1);
    }
    __syncthreads();
    for (int c = tt; c < S; c += 256) {
      const int v = lh[c];
      if (v) atomicAdd(&cnt[c], v);
    }
  }
}

// ---- BN0 stats via MFMA (h bitwise == k_main's) + fused last-block reduce -> st0 ----
__global__ void k_hsq(const short* __restrict__ featb, const int* __restrict__ cnt,
                      const short* __restrict__ w0f, float* __restrict__ p0,
                      int* __restrict__ ctr, const float* __restrict__ g0,
                      const float* __restrict__ b0, float* __restrict__ st0) {
  __shared__ float sred[4][2][64];
  __shared__ int isLast;
  const int t = threadIdx.x, blk = blockIdx.x;
  const int wv = t >> 6, ln = t & 63, l4 = ln >> 4, l15 = ln & 15;

  const bf16x8* w0v = (const bf16x8*)w0f;
  bf16x8 w0a[8];
#pragma unroll
  for (int fa = 0; fa < 8; ++fa) w0a[fa] = w0v[fa * 64 + ln];

  const int s0 = blk * 64 + wv * 16;
  const float wc = (float)cnt[s0 + l15];
  const short* fb = featb + (size_t)(s0 + l15) * F + 8 * l4;
  const bf16x8 y0 = *(const bf16x8*)(fb);
  const bf16x8 y1 = *(const bf16x8*)(fb + 32);

  float hs[4][4], hq[4][4];
#pragma unroll
  for (int mt = 0; mt < 4; ++mt) {
    f32x4 acc = {0.f, 0.f, 0.f, 0.f};
    acc = __builtin_amdgcn_mfma_f32_16x16x32_bf16(w0a[2 * mt], y0, acc, 0, 0, 0);
    acc = __builtin_amdgcn_mfma_f32_16x16x32_bf16(w0a[2 * mt + 1], y1, acc, 0, 0, 0);
#pragma unroll
    for (int r = 0; r < 4; ++r) {
      const float h = acc[r];
      hs[mt][r] = wc * h;
      hq[mt][r] = wc * h * h;
    }
  }
#pragma unroll
  for (int mt = 0; mt < 4; ++mt)
#pragma unroll
    for (int r = 0; r < 4; ++r) {
      float s = hs[mt][r], q = hq[mt][r];
#pragma unroll
      for (int d = 1; d < 16; d <<= 1) { s += __shfl_xor(s, d); q += __shfl_xor(q, d); }
      hs[mt][r] = s; hq[mt][r] = q;
    }
  if (l15 == 0) {
#pragma unroll
    for (int mt = 0; mt < 4; ++mt)
#pragma unroll
      for (int r = 0; r < 4; ++r) {
        const int o = 16 * mt + 4 * l4 + r;
        sred[wv][0][o] = hs[mt][r];
        sred[wv][1][o] = hq[mt][r];
      }
  }
  __syncthreads();
  if (t < 128) {
    const int qq = t >> 6, o = t & 63;
    p0[(size_t)blk * 128 + t] =
        sred[0][qq][o] + sred[1][qq][o] + sred[2][qq][o] + sred[3][qq][o];
  }
  // last-block reduction -> st0 (deterministic fixed order)
  __syncthreads();
  __threadfence();
  if (t == 0) isLast = (atomicAdd(&ctr[0], 1) == GH - 1);
  __syncthreads();
  if (isLast) {
    __threadfence();
    if (t < O) {
      float s = 0.f, q = 0.f;
      for (int b = 0; b < GH; ++b) {
        s += p0[(size_t)b * 128 + t];
        q += p0[(size_t)b * 128 + 64 + t];
      }
      const float invN = 1.f / (float)NEDGE;
      const float mean = s * invN;
      const float var = q * invN - mean * mean;
      const float sc = g0[t] * rsqrtf(var + EPSV);
      st0[t] = sc;
      st0[O + t] = b0[t] - mean * sc;
    }
  }
}

// ---- main MFMA pass: sigma-permuted k, 2-deep pipelined Phase A, reg-resident H ----
__launch_bounds__(256, 2)
__global__ void k_main(const float* __restrict__ qpts, const float* __restrict__ spts,
                       const short* __restrict__ featb, const int* __restrict__ inds,
                       const short* __restrict__ w0f, const short* __restrict__ w1f,
                       const float* __restrict__ st0,
                       float* __restrict__ zmax, float* __restrict__ zmin,
                       float* __restrict__ p1) {
  __shared__ __align__(16) float xs[3 * EB];      // x per edge
  __shared__ float swred[512];                    // block-sum staging

  const int t = threadIdx.x, blk = blockIdx.x;
  const int wv = t >> 6, ln = t & 63, l4 = ln >> 4, l15 = ln & 15;
  const int ebase = blk * EB;

  // ---- stage x (wave-local rows; same-wave DS ordering, no barrier needed)
  const int idx0 = inds[ebase + t];
  {
    const int q = blk * QB + (t >> 5);
    float x0 = 0.f, x1 = 0.f, x2 = 0.f;
    if (idx0 < S) {
      x0 = spts[idx0 * 3 + 0] - qpts[q * 3 + 0];
      x1 = spts[idx0 * 3 + 1] - qpts[q * 3 + 1];
      x2 = spts[idx0 * 3 + 2] - qpts[q * 3 + 2];
    }
    xs[0 * EB + t] = x0; xs[1 * EB + t] = x1; xs[2 * EB + t] = x2;
  }

  // per-tile indices via intra-wave shuffle of the staged load (no 2nd global read)
  int idxT[4];
#pragma unroll
  for (int nt = 0; nt < 4; ++nt) idxT[nt] = __shfl(idx0, nt * 16 + l15, 64);

  // W0 A-frags (L2-hot, coalesced)
  const bf16x8* w0v = (const bf16x8*)w0f;
  bf16x8 w0a[8];
#pragma unroll
  for (int fa = 0; fa < 8; ++fa) w0a[fa] = w0v[fa * 64 + ln];

  const float* scp = st0 + 4 * l4;        // sc[o=16m+4l4+r] = scp[16m+r]
  const float* shp = st0 + O + 4 * l4;

  // helpers (inlined; all indices compile-time)
  auto loadY = [&](int idx, bf16x8& y0, bf16x8& y1) {
    if (idx < S) {
      const short* fbp = featb + (size_t)idx * F + 8 * l4;
      y0 = *(const bf16x8*)(fbp);
      y1 = *(const bf16x8*)(fbp + 32);
    } else {
#pragma unroll
      for (int j = 0; j < 8; ++j) { y0[j] = 0; y1[j] = 0; }
    }
  };
  auto tileA = [&](const bf16x8& y0, const bf16x8& y1, bf16x8& h0, bf16x8& h1) {
#pragma unroll
    for (int kk = 0; kk < 2; ++kk) {
      f32x4 a0 = {0.f, 0.f, 0.f, 0.f}, a1 = {0.f, 0.f, 0.f, 0.f};
      a0 = __builtin_amdgcn_mfma_f32_16x16x32_bf16(w0a[4 * kk + 0], y0, a0, 0, 0, 0);
      a0 = __builtin_amdgcn_mfma_f32_16x16x32_bf16(w0a[4 * kk + 1], y1, a0, 0, 0, 0);
      a1 = __builtin_amdgcn_mfma_f32_16x16x32_bf16(w0a[4 * kk + 2], y0, a1, 0, 0, 0);
      a1 = __builtin_amdgcn_mfma_f32_16x16x32_bf16(w0a[4 * kk + 3], y1, a1, 0, 0, 0);
      const f32x4 sc0 = *(const f32x4*)(scp + 32 * kk);
      const f32x4 sh0 = *(const f32x4*)(shp + 32 * kk);
      const f32x4 sc1 = *(const f32x4*)(scp + 32 * kk + 16);
      const f32x4 sh1 = *(const f32x4*)(shp + 32 * kk + 16);
      bf16x8 h;
#pragma unroll
      for (int r = 0; r < 4; ++r) {
        float v = a0[r] * sc0[r] + sh0[r];
        v = fmaxf(v, 0.1f * v);
        h[r] = f2bf(v);
      }
#pragma unroll
      for (int r = 0; r < 4; ++r) {
        float v = a1[r] * sc1[r] + sh1[r];
        v = fmaxf(v, 0.1f * v);
        h[4 + r] = f2bf(v);
      }
      if (kk == 0) h0 = h; else h1 = h;
    }
  };

  // ---- Phase A: 2-deep pipeline (only 2 y-pairs in flight => low VGPR peak)
  bf16x8 hA[4][2];
  {
    bf16x8 ya0, ya1, yb0, yb1;
    loadY(idxT[0], ya0, ya1);
    loadY(idxT[1], yb0, yb1);
    tileA(ya0, ya1, hA[0][0], hA[0][1]);
    loadY(idxT[2], ya0, ya1);
    tileA(yb0, yb1, hA[1][0], hA[1][1]);
    loadY(idxT[3], yb0, yb1);
    tileA(ya0, ya1, hA[2][0], hA[2][1]);
    tileA(yb0, yb1, hA[3][0], hA[3][1]);
  }

  const bf16x8* w1v = (const bf16x8*)w1f;
  float zmx[2][4], zmn[2][4], zs[4], zq[4];
#pragma unroll
  for (int j = 0; j < 4; ++j) {
    zs[j] = 0.f; zq[j] = 0.f;
    zmx[0][j] = -3.4e38f; zmx[1][j] = -3.4e38f;
    zmn[0][j] = 3.4e38f;  zmn[1][j] = 3.4e38f;
  }

  // ---- Phase B: D2[e][c=i*64+o] = H * W1p (sigma-consistent) ; combine with x ; stats
#pragma unroll
  for (int b = 0; b < 4; ++b) {
    bf16x8 w1b[6];
#pragma unroll
    for (int i = 0; i < 3; ++i)
#pragma unroll
      for (int kk = 0; kk < 2; ++kk)
        w1b[i * 2 + kk] = w1v[(((i * 4 + b) * 2) + kk) * 64 + ln];
#pragma unroll
    for (int mt = 0; mt < 4; ++mt) {
      const int ex = wv * 64 + mt * 16 + 4 * l4;
      f32x4 z4 = {0.f, 0.f, 0.f, 0.f};
#pragma unroll
      for (int i = 0; i < 3; ++i) {
        f32x4 acc = {0.f, 0.f, 0.f, 0.f};
        acc = __builtin_amdgcn_mfma_f32_16x16x32_bf16(hA[mt][0], w1b[2 * i], acc, 0, 0, 0);
        acc = __builtin_amdgcn_mfma_f32_16x16x32_bf16(hA[mt][1], w1b[2 * i + 1], acc, 0, 0, 0);
        const f32x4 xv = *(const f32x4*)&xs[i * EB + ex];
#pragma unroll
        for (int r = 0; r < 4; ++r) z4[r] += acc[r] * xv[r];
      }
      const int qh = mt >> 1;
#pragma unroll
      for (int r = 0; r < 4; ++r) {
        const float v = z4[r];
        zmx[qh][b] = fmaxf(zmx[qh][b], v);
        zmn[qh][b] = fminf(zmn[qh][b], v);
        zs[b] += v; zq[b] += v * v;
      }
    }
  }

  // ---- cross-group (l4) reductions: lanes l, l^16, l^32 share (q-range, c)
#pragma unroll
  for (int qh = 0; qh < 2; ++qh)
#pragma unroll
    for (int b = 0; b < 4; ++b) {
      float m = zmx[qh][b];
      m = fmaxf(m, __shfl_xor(m, 16)); m = fmaxf(m, __shfl_xor(m, 32));
      zmx[qh][b] = m;
      float n = zmn[qh][b];
      n = fminf(n, __shfl_xor(n, 16)); n = fminf(n, __shfl_xor(n, 32));
      zmn[qh][b] = n;
    }
#pragma unroll
  for (int b = 0; b < 4; ++b) {
    float s = zs[b];  s += __shfl_xor(s, 16);  s += __shfl_xor(s, 32);  zs[b] = s;
    float sq = zq[b]; sq += __shfl_xor(sq, 16); sq += __shfl_xor(sq, 32); zq[b] = sq;
  }

  if (l4 == 0) {
#pragma unroll
    for (int qh = 0; qh < 2; ++qh) {
      const int q = blk * QB + wv * 2 + qh;
#pragma unroll
      for (int b = 0; b < 4; ++b) {
        zmax[(size_t)q * O + 16 * b + l15] = zmx[qh][b];
        zmin[(size_t)q * O + 16 * b + l15] = zmn[qh][b];
      }
    }
#pragma unroll
    for (int b = 0; b < 4; ++b) {
      swred[wv * 128 + 16 * b + l15] = zs[b];
      swred[wv * 128 + 64 + 16 * b + l15] = zq[b];
    }
  }
  __syncthreads();
  if (t < 128)
    p1[(size_t)blk * 128 + t] = swred[t] + swred[128 + t] + swred[256 + t] + swred[384 + t];
}

// ---- reduce z stats + BN1 scale/shift ----
__global__ void k_red1(const float* __restrict__ p1, const float* __restrict__ g1,
                       const float* __restrict__ b1, float* __restrict__ st1) {
  __shared__ float rs[256], rq[256];
  const int o = blockIdx.x, t = threadIdx.x;
  float s = 0.f, q = 0.f;
  for (int r = t; r < GD; r += 256) {
    s += p1[(size_t)r * 128 + o];
    q += p1[(size_t)r * 128 + 64 + o];
  }
  rs[t] = s; rq[t] = q;
  __syncthreads();
  for (int off = 128; off > 0; off >>= 1) {
    if (t < off) { rs[t] += rs[t + off]; rq[t] += rq[t + off]; }
    __syncthreads();
  }
  if (t == 0) {
    const float invN = 1.f / (float)NEDGE;
    const float mean = rs[0] * invN;
    const float var = rq[0] * invN - mean * mean;
    const float sc = g1[o] * rsqrtf(var + EPSV);
    st1[o] = sc;
    st1[O + o] = b1[o] - mean * sc;
  }
}

// ---- finalize: pick max/min by scale sign, affine + leaky (vectorized) ----
__global__ void k_final(const float* __restrict__ st1, const float* __restrict__ zmin,
                        float* __restrict__ out) {
  const int i4 = blockIdx.x * blockDim.x + threadIdx.x;   // Q*O/4 elements
  const int o0 = (i4 * 4) & 63;
  const f32x4 mx = *(const f32x4*)(out + (size_t)i4 * 4);   // holds zmax
  const f32x4 mn = *(const f32x4*)(zmin + (size_t)i4 * 4);
  const f32x4 sc = *(const f32x4*)(st1 + o0);
  const f32x4 sh = *(const f32x4*)(st1 + O + o0);
  f32x4 r;
#pragma unroll
  for (int j = 0; j < 4; ++j) {
    const float base = (sc[j] >= 0.f) ? mx[j] : mn[j];
    const float v = base * sc[j] + sh[j];
    r[j] = fmaxf(v, 0.1f * v);
  }
  *(f32x4*)(out + (size_t)i4 * 4) = r;
}

extern "C" void kernel_launch(void* const* d_in, const int* in_sizes, int n_in,
                              void* d_out, int out_size, void* d_ws, size_t ws_size,
                              hipStream_t stream) {
  const float* qpts = (const float*)d_in[0];
  const float* spts = (const float*)d_in[1];
  const float* feat = (const float*)d_in[2];
  const int*   inds = (const int*)d_in[3];
  const float* w0   = (const float*)d_in[4];
  const float* g0   = (const float*)d_in[5];
  const float* b0   = (const float*)d_in[6];
  const float* w1   = (const float*)d_in[7];
  const float* g1   = (const float*)d_in[8];
  const float* b1   = (const float*)d_in[9];
  float* out = (float*)d_out;

  char* ws = (char*)d_ws;
  int*   cnt   = (int*)(ws + CNT_OFF);
  int*   ctr   = (int*)(ws + CTR_OFF);
  float* p0    = (float*)(ws + P0_OFF);
  float* st0   = (float*)(ws + ST0_OFF);
  float* zmin  = (float*)(ws + ZMIN_OFF);
  float* p1    = (float*)(ws + P1_OFF);
  float* st1   = (float*)(ws + ST1_OFF);
  short* w0f   = (short*)(ws + W0F_OFF);
  short* w1f   = (short*)(ws + W1F_OFF);
  short* featb = (short*)(ws + FEATB_OFF);

  hipMemsetAsync(ws, 0, CTR_OFF + 64, stream);   // cnt + ticket counters
  k_prep_hist<<<136, 256, 0, stream>>>(w0, w1, w0f, w1f, feat, featb, inds, cnt);
  k_hsq<<<GH, 256, 0, stream>>>(featb, cnt, w0f, p0, ctr, g0, b0, st0);
  k_main<<<GD, 256, 0, stream>>>(qpts, spts, featb, inds, w0f, w1f, st0, out, zmin, p1);
  k_red1<<<64, 256, 0, stream>>>(p1, g1, b1, st1);
  k_final<<<(Q * O) / 1024, 256, 0, stream>>>(st1, zmin, out);
}